// Round 5
// baseline (83.819 us; speedup 1.0000x reference)
//
#include <hip/hip_runtime.h>
#include <stdint.h>

typedef __attribute__((ext_vector_type(8))) __bf16 bf16x8;
typedef __attribute__((ext_vector_type(4))) float f32x4;
typedef __attribute__((ext_vector_type(16))) float f32x16;

__device__ __forceinline__ unsigned short f2bf(float f) {
  union { float f; unsigned int u; } v; v.f = f;
  unsigned int u = v.u;
  return (unsigned short)((u + 0x7fffu + ((u >> 16) & 1u)) >> 16);
}

__device__ __forceinline__ void async_copy16(const void* g, void* s) {
  __builtin_amdgcn_global_load_lds(
      (__attribute__((address_space(1))) void*)const_cast<void*>(g),
      (__attribute__((address_space(3))) void*)s,
      16, 0, 0);
}

#define HAAR(a, bb, cc, dd, oA, oH, oV, oD)                                    \
  oA = 0.5f * ((a + bb) + (cc + dd));                                          \
  oH = 0.5f * ((a + bb) - (cc + dd));                                          \
  oV = 0.5f * ((a - bb) + (cc - dd));                                          \
  oD = 0.5f * ((a - bb) - (cc - dd));

// ---------------- W fp32 -> bf16 (already [N=768][K=768] row-major) --------
__global__ __launch_bounds__(256) void convw_kernel(const float* __restrict__ W,
                                                    unsigned short* __restrict__ Wb) {
  int i = blockIdx.x * 256 + threadIdx.x;  // 147456 threads x 4 floats
  float4 v = ((const float4*)W)[i];
  uint2 o;
  o.x = (unsigned int)f2bf(v.x) | ((unsigned int)f2bf(v.y) << 16);
  o.y = (unsigned int)f2bf(v.z) | ((unsigned int)f2bf(v.w) << 16);
  ((uint2*)Wb)[i] = o;
}

// ------- 2-level Haar DWT -> bf16 A[M=25088][K=768] in patch layout --------
__global__ __launch_bounds__(256) void dwt2_kernel(const float* __restrict__ x,
                                                   unsigned short* __restrict__ A) {
  int tid = blockIdx.x * 256 + threadIdx.x;  // 128*3*56*56 = 1204224
  int J = tid % 56;
  int t = tid / 56;
  int I = t % 56;
  t /= 56;  // t = b*3 + c
  int c = t % 3;
  int b = t / 3;

  const float* xp = x + (((size_t)t * 224 + 4 * I) * 224 + 4 * J);
  float4 r0 = *(const float4*)(xp);
  float4 r1 = *(const float4*)(xp + 224);
  float4 r2 = *(const float4*)(xp + 448);
  float4 r3 = *(const float4*)(xp + 672);

  float A1[2][2], H1[2][2], V1[2][2], D1[2][2];
  HAAR(r0.x, r0.y, r1.x, r1.y, A1[0][0], H1[0][0], V1[0][0], D1[0][0]);
  HAAR(r0.z, r0.w, r1.z, r1.w, A1[0][1], H1[0][1], V1[0][1], D1[0][1]);
  HAAR(r2.x, r2.y, r3.x, r3.y, A1[1][0], H1[1][0], V1[1][0], D1[1][0]);
  HAAR(r2.z, r2.w, r3.z, r3.w, A1[1][1], H1[1][1], V1[1][1], D1[1][1]);

  auto aidx = [&](int y, int xx) -> size_t {
    int mrow = b * 196 + (y >> 4) * 14 + (xx >> 4);
    int k = c * 256 + (y & 15) * 16 + (xx & 15);
    return (size_t)mrow * 768 + (size_t)k;
  };
  auto store2 = [&](int y, int xx, float v0, float v1) {
    unsigned int p = (unsigned int)f2bf(v0) | ((unsigned int)f2bf(v1) << 16);
    *(unsigned int*)(A + aidx(y, xx)) = p;  // xx even -> 4B aligned, same patch
  };

  int y0 = 2 * I, x0 = 2 * J;
  store2(y0,           112 + x0, H1[0][0], H1[0][1]);
  store2(y0 + 1,       112 + x0, H1[1][0], H1[1][1]);
  store2(112 + y0,     x0,       V1[0][0], V1[0][1]);
  store2(112 + y0 + 1, x0,       V1[1][0], V1[1][1]);
  store2(112 + y0,     112 + x0, D1[0][0], D1[0][1]);
  store2(112 + y0 + 1, 112 + x0, D1[1][0], D1[1][1]);

  float vA2, vH2, vV2, vD2;
  HAAR(A1[0][0], A1[0][1], A1[1][0], A1[1][1], vA2, vH2, vV2, vD2);
  A[aidx(I,      J)]      = f2bf(vA2);
  A[aidx(I,      56 + J)] = f2bf(vH2);
  A[aidx(56 + I, J)]      = f2bf(vV2);
  A[aidx(56 + I, 56 + J)] = f2bf(vD2);
}

// --------- bf16 MFMA GEMM: C[M][N] = A[M][K] * Bt[N][K]^T + bias -----------
// M=25088, N=768, K=768. 128x128 block, BK=32, TWO waves of 64x128 each
// (fat waves: LDS bytes/FLOP = 0.0234, under the ds_read BW budget).
// 32x32x16 MFMA. Double-buffered LDS (32 KB) -> 4 blocks/CU for TLP.
// Chunk-XOR LDS swizzle, counted-vmcnt pipeline, raw s_barrier.
__global__ __launch_bounds__(128, 2) void gemm_kernel(const unsigned short* __restrict__ A,
                                                      const unsigned short* __restrict__ Bt,
                                                      const float* __restrict__ bias,
                                                      float* __restrict__ C) {
  constexpr int K = 768, N = 768;
  constexpr int NT = 24;  // K / 32
  __shared__ unsigned short As[2][128 * 32];  // 8 KB per buffer
  __shared__ unsigned short Bs[2][128 * 32];

  // XCD swizzle: 1176 tiles = 8 XCDs x 147 consecutive tiles (bijective).
  const int orig = blockIdx.x;
  const int tile = (orig & 7) * 147 + (orig >> 3);
  const int bm = tile / 6, bn = tile % 6;

  const int tid = threadIdx.x;
  const int lane = tid & 63;
  const int wave = tid >> 6;  // 0..1 ; wave tile = rows [wave*64, +64) x all 128 cols
  const int mbase = bm * 128, nbase = bn * 128;

  f32x16 acc[2][4] = {};  // [m-tile 32][n-tile 32] per wave: 64x128

  // --- staging: inst i covers LDS bytes [i*2048 + wave*1024 + lane*16) ---
  // physical (row, chunk); source chunk pre-swizzled (involution).
  const unsigned short* gA[4];
  const unsigned short* gB[4];
#pragma unroll
  for (int i = 0; i < 4; ++i) {
    int off = i * 2048 + wave * 1024 + lane * 16;
    int row = off >> 6;              // 0..127
    int kc = (off >> 4) & 3;
    int kcs = kc ^ ((row >> 1) & 3); // swizzled source chunk
    gA[i] = A + (size_t)(mbase + row) * K + kcs * 8;
    gB[i] = Bt + (size_t)(nbase + row) * K + kcs * 8;
  }

  auto stage = [&](int buf, int kt) {
    char* sa = (char*)As + buf * 8192 + wave * 1024;
    char* sb = (char*)Bs + buf * 8192 + wave * 1024;
    const int ko = kt * 32;
#pragma unroll
    for (int i = 0; i < 4; ++i) {
      async_copy16(gA[i] + ko, sa + i * 2048);
      async_copy16(gB[i] + ko, sb + i * 2048);
    }
  };

  // fragment read geometry (32x32x16): row-in-tile = lane&31, k-half = lane>>5
  const int fr = lane & 31;
  const int kh = lane >> 5;
  const int swz = (fr >> 1) & 3;
  const int c0 = (kh ^ swz) * 16;        // k-step 0: chunks {0,1}
  const int c1 = ((2 + kh) ^ swz) * 16;  // k-step 1: chunks {2,3}

  stage(0, 0);

#pragma unroll
  for (int kt = 0; kt < NT; ++kt) {
    asm volatile("s_waitcnt vmcnt(0)" ::: "memory");  // tile kt landed
    __builtin_amdgcn_s_barrier();                     // visible to both waves
    if (kt + 1 < NT) stage((kt + 1) & 1, kt + 1);     // prefetch next K-tile

    const char* pa = (const char*)As + (kt & 1) * 8192 + (wave * 64 + fr) * 64;
    const char* pb = (const char*)Bs + (kt & 1) * 8192 + fr * 64;
#pragma unroll
    for (int s = 0; s < 2; ++s) {  // two 16-k MFMA steps per 32-k tile
      const int cc = s ? c1 : c0;
      bf16x8 af[2], bv[4];
      af[0] = *(const bf16x8*)(pa + cc);
      af[1] = *(const bf16x8*)(pa + 32 * 64 + cc);
      bv[0] = *(const bf16x8*)(pb + cc);
      bv[1] = *(const bf16x8*)(pb + 32 * 64 + cc);
      bv[2] = *(const bf16x8*)(pb + 64 * 64 + cc);
      bv[3] = *(const bf16x8*)(pb + 96 * 64 + cc);
#pragma unroll
      for (int mt = 0; mt < 2; ++mt)
#pragma unroll
        for (int nt = 0; nt < 4; ++nt)
          acc[mt][nt] = __builtin_amdgcn_mfma_f32_32x32x16_bf16(
              af[mt], bv[nt], acc[mt][nt], 0, 0, 0);
    }
    asm volatile("s_waitcnt lgkmcnt(0)" ::: "memory");  // reads done pre-barrier
  }

  // epilogue: 32x32 C/D layout: col=lane&31, row=(r&3)+8*(r>>2)+4*(lane>>5)
  const int col = lane & 31;
  const int rowoff = 4 * kh;
#pragma unroll
  for (int nt = 0; nt < 4; ++nt) {
    int n = nbase + nt * 32 + col;
    float bb = bias[n];
#pragma unroll
    for (int mt = 0; mt < 2; ++mt) {
      f32x16 v = acc[mt][nt];
#pragma unroll
      for (int r = 0; r < 16; ++r) {
        int mrow = mbase + wave * 64 + mt * 32 + (r & 3) + 8 * (r >> 2) + rowoff;
        C[(size_t)mrow * N + n] = v[r] + bb;
      }
    }
  }
}

extern "C" void kernel_launch(void* const* d_in, const int* in_sizes, int n_in,
                              void* d_out, int out_size, void* d_ws, size_t ws_size,
                              hipStream_t stream) {
  const float* x = (const float*)d_in[0];     // (128,3,224,224) f32
  const float* W = (const float*)d_in[1];     // (768,3,16,16)  f32
  const float* bias = (const float*)d_in[2];  // (768,)         f32
  float* out = (float*)d_out;                 // (128,196,768)  f32

  unsigned short* A = (unsigned short*)d_ws;                        // 25088*768 bf16
  unsigned short* Wb = (unsigned short*)((char*)d_ws + 38535168);   // 589824 bf16

  convw_kernel<<<576, 256, 0, stream>>>(W, Wb);
  dwt2_kernel<<<4704, 256, 0, stream>>>(x, A);
  gemm_kernel<<<1176, 128, 0, stream>>>(A, Wb, bias, out);
}

// Round 6
// 78.608 us; speedup vs baseline: 1.0663x; 1.0663x over previous
//
#include <hip/hip_runtime.h>
#include <stdint.h>

typedef __attribute__((ext_vector_type(8))) __bf16 bf16x8;
typedef __attribute__((ext_vector_type(4))) float f32x4;
typedef __attribute__((ext_vector_type(16))) float f32x16;

__device__ __forceinline__ unsigned short f2bf(float f) {
  union { float f; unsigned int u; } v; v.f = f;
  unsigned int u = v.u;
  return (unsigned short)((u + 0x7fffu + ((u >> 16) & 1u)) >> 16);
}

__device__ __forceinline__ void async_copy16(const void* g, void* s) {
  __builtin_amdgcn_global_load_lds(
      (__attribute__((address_space(1))) void*)const_cast<void*>(g),
      (__attribute__((address_space(3))) void*)s,
      16, 0, 0);
}

#define HAAR(a, bb, cc, dd, oA, oH, oV, oD)                                    \
  oA = 0.5f * ((a + bb) + (cc + dd));                                          \
  oH = 0.5f * ((a + bb) - (cc + dd));                                          \
  oV = 0.5f * ((a - bb) + (cc - dd));                                          \
  oD = 0.5f * ((a - bb) - (cc - dd));

// ---------------- W fp32 -> bf16 (already [N=768][K=768] row-major) --------
__global__ __launch_bounds__(256) void convw_kernel(const float* __restrict__ W,
                                                    unsigned short* __restrict__ Wb) {
  int i = blockIdx.x * 256 + threadIdx.x;  // 147456 threads x 4 floats
  float4 v = ((const float4*)W)[i];
  uint2 o;
  o.x = (unsigned int)f2bf(v.x) | ((unsigned int)f2bf(v.y) << 16);
  o.y = (unsigned int)f2bf(v.z) | ((unsigned int)f2bf(v.w) << 16);
  ((uint2*)Wb)[i] = o;
}

// ------- 2-level Haar DWT -> bf16 A[M=25088][K=768] in patch layout --------
__global__ __launch_bounds__(256) void dwt2_kernel(const float* __restrict__ x,
                                                   unsigned short* __restrict__ A) {
  int tid = blockIdx.x * 256 + threadIdx.x;  // 128*3*56*56 = 1204224
  int J = tid % 56;
  int t = tid / 56;
  int I = t % 56;
  t /= 56;  // t = b*3 + c
  int c = t % 3;
  int b = t / 3;

  const float* xp = x + (((size_t)t * 224 + 4 * I) * 224 + 4 * J);
  float4 r0 = *(const float4*)(xp);
  float4 r1 = *(const float4*)(xp + 224);
  float4 r2 = *(const float4*)(xp + 448);
  float4 r3 = *(const float4*)(xp + 672);

  float A1[2][2], H1[2][2], V1[2][2], D1[2][2];
  HAAR(r0.x, r0.y, r1.x, r1.y, A1[0][0], H1[0][0], V1[0][0], D1[0][0]);
  HAAR(r0.z, r0.w, r1.z, r1.w, A1[0][1], H1[0][1], V1[0][1], D1[0][1]);
  HAAR(r2.x, r2.y, r3.x, r3.y, A1[1][0], H1[1][0], V1[1][0], D1[1][0]);
  HAAR(r2.z, r2.w, r3.z, r3.w, A1[1][1], H1[1][1], V1[1][1], D1[1][1]);

  auto aidx = [&](int y, int xx) -> size_t {
    int mrow = b * 196 + (y >> 4) * 14 + (xx >> 4);
    int k = c * 256 + (y & 15) * 16 + (xx & 15);
    return (size_t)mrow * 768 + (size_t)k;
  };
  auto store2 = [&](int y, int xx, float v0, float v1) {
    unsigned int p = (unsigned int)f2bf(v0) | ((unsigned int)f2bf(v1) << 16);
    *(unsigned int*)(A + aidx(y, xx)) = p;  // xx even -> 4B aligned, same patch
  };

  int y0 = 2 * I, x0 = 2 * J;
  store2(y0,           112 + x0, H1[0][0], H1[0][1]);
  store2(y0 + 1,       112 + x0, H1[1][0], H1[1][1]);
  store2(112 + y0,     x0,       V1[0][0], V1[0][1]);
  store2(112 + y0 + 1, x0,       V1[1][0], V1[1][1]);
  store2(112 + y0,     112 + x0, D1[0][0], D1[0][1]);
  store2(112 + y0 + 1, 112 + x0, D1[1][0], D1[1][1]);

  float vA2, vH2, vV2, vD2;
  HAAR(A1[0][0], A1[0][1], A1[1][0], A1[1][1], vA2, vH2, vV2, vD2);
  A[aidx(I,      J)]      = f2bf(vA2);
  A[aidx(I,      56 + J)] = f2bf(vH2);
  A[aidx(56 + I, J)]      = f2bf(vV2);
  A[aidx(56 + I, 56 + J)] = f2bf(vD2);
}

// --------- bf16 MFMA GEMM: C[M][N] = A[M][K] * Bt[N][K]^T + bias -----------
// M=25088, N=768, K=768. 128x128 block, BK=32, TWO waves of 64x128
// (0.0234 LDS-B/FLOP). 32x32x16 MFMA. Triple-buffered LDS (48 KB ->
// 3 blocks/CU), prefetch depth 2, counted vmcnt(8) + raw s_barrier.
// Conflict-free XOR swizzle P(row)=(row>>3)&3: every (row-parity, chunk)
// bank-slot gets exactly 8/64 lanes on each ds_read_b128.
__global__ __launch_bounds__(128, 2) void gemm_kernel(const unsigned short* __restrict__ A,
                                                      const unsigned short* __restrict__ Bt,
                                                      const float* __restrict__ bias,
                                                      float* __restrict__ C) {
  constexpr int K = 768, N = 768;
  constexpr int NT = 24;  // K / 32
  __shared__ unsigned short As[3][128 * 32];  // 8 KB per buffer
  __shared__ unsigned short Bs[3][128 * 32];

  // XCD swizzle: 1176 tiles = 8 XCDs x 147 consecutive tiles (bijective).
  const int orig = blockIdx.x;
  const int tile = (orig & 7) * 147 + (orig >> 3);
  const int bm = tile / 6, bn = tile % 6;

  const int tid = threadIdx.x;
  const int lane = tid & 63;
  const int wave = tid >> 6;  // 0..1 ; wave tile = rows [wave*64, +64) x all 128 cols
  const int mbase = bm * 128, nbase = bn * 128;

  f32x16 acc[2][4] = {};  // [m-tile 32][n-tile 32] per wave: 64x128

  // --- staging: inst i covers LDS bytes [i*2048 + wave*1024 + lane*16) ---
  // dest row = i*32 + wave*16 + (lane>>2), phys chunk = lane&3.
  // source logical chunk = phys ^ P(row); P(row)=(row>>3)&3 and
  // (row>>3)&3 = (wave*2 + (lane>>5)) & 3  (i*4 drops mod 4).
  const int row0 = wave * 16 + (lane >> 2);
  const int kcs = (lane & 3) ^ ((wave * 2 + (lane >> 5)) & 3);
  const unsigned short* gA[4];
  const unsigned short* gB[4];
#pragma unroll
  for (int i = 0; i < 4; ++i) {
    gA[i] = A + (size_t)(mbase + i * 32 + row0) * K + kcs * 8;
    gB[i] = Bt + (size_t)(nbase + i * 32 + row0) * K + kcs * 8;
  }

  auto stage = [&](int buf, int kt) {
    char* sa = (char*)As + buf * 8192 + wave * 1024;
    char* sb = (char*)Bs + buf * 8192 + wave * 1024;
    const int ko = kt * 32;
#pragma unroll
    for (int i = 0; i < 4; ++i) {
      async_copy16(gA[i] + ko, sa + i * 2048);
      async_copy16(gB[i] + ko, sb + i * 2048);
    }
  };

  // fragment read geometry (32x32x16): row-in-tile fr = lane&31, kh = lane>>5
  // logical chunk = 2s + kh ; physical = logical ^ P(fr), P = (fr>>3)&3
  const int fr = lane & 31;
  const int kh = lane >> 5;
  const int P = (fr >> 3) & 3;
  const int c0 = (kh ^ P) * 16;        // k-step 0
  const int c1 = ((2 + kh) ^ P) * 16;  // k-step 1

  stage(0, 0);
  stage(1, 1);

#pragma unroll
  for (int kt = 0; kt < NT; ++kt) {
    if (kt < NT - 1)
      asm volatile("s_waitcnt vmcnt(8)" ::: "memory");  // tile kt landed
    else
      asm volatile("s_waitcnt vmcnt(0)" ::: "memory");
    __builtin_amdgcn_s_barrier();       // tile kt visible; prev reads done
    if (kt + 2 < NT) stage((kt + 2) % 3, kt + 2);

    const char* pa = (const char*)As + (kt % 3) * 8192 + (wave * 64 + fr) * 64;
    const char* pb = (const char*)Bs + (kt % 3) * 8192 + fr * 64;
#pragma unroll
    for (int s = 0; s < 2; ++s) {  // two 16-k MFMA steps per 32-k tile
      const int cc = s ? c1 : c0;
      bf16x8 af[2], bv[4];
      af[0] = *(const bf16x8*)(pa + cc);
      af[1] = *(const bf16x8*)(pa + 32 * 64 + cc);
      bv[0] = *(const bf16x8*)(pb + cc);
      bv[1] = *(const bf16x8*)(pb + 32 * 64 + cc);
      bv[2] = *(const bf16x8*)(pb + 64 * 64 + cc);
      bv[3] = *(const bf16x8*)(pb + 96 * 64 + cc);
#pragma unroll
      for (int mt = 0; mt < 2; ++mt)
#pragma unroll
        for (int nt = 0; nt < 4; ++nt)
          acc[mt][nt] = __builtin_amdgcn_mfma_f32_32x32x16_bf16(
              af[mt], bv[nt], acc[mt][nt], 0, 0, 0);
    }
    asm volatile("s_waitcnt lgkmcnt(0)" ::: "memory");  // reads done pre-barrier
  }

  // epilogue: 32x32 C/D layout: col=lane&31, row=(r&3)+8*(r>>2)+4*(lane>>5)
  const int col = lane & 31;
  const int rowoff = 4 * kh;
#pragma unroll
  for (int nt = 0; nt < 4; ++nt) {
    int n = nbase + nt * 32 + col;
    float bb = bias[n];
#pragma unroll
    for (int mt = 0; mt < 2; ++mt) {
      f32x16 v = acc[mt][nt];
#pragma unroll
      for (int r = 0; r < 16; ++r) {
        int mrow = mbase + wave * 64 + mt * 32 + (r & 3) + 8 * (r >> 2) + rowoff;
        C[(size_t)mrow * N + n] = v[r] + bb;
      }
    }
  }
}

extern "C" void kernel_launch(void* const* d_in, const int* in_sizes, int n_in,
                              void* d_out, int out_size, void* d_ws, size_t ws_size,
                              hipStream_t stream) {
  const float* x = (const float*)d_in[0];     // (128,3,224,224) f32
  const float* W = (const float*)d_in[1];     // (768,3,16,16)  f32
  const float* bias = (const float*)d_in[2];  // (768,)         f32
  float* out = (float*)d_out;                 // (128,196,768)  f32

  unsigned short* A = (unsigned short*)d_ws;                        // 25088*768 bf16
  unsigned short* Wb = (unsigned short*)((char*)d_ws + 38535168);   // 589824 bf16

  convw_kernel<<<576, 256, 0, stream>>>(W, Wb);
  dwt2_kernel<<<4704, 256, 0, stream>>>(x, A);
  gemm_kernel<<<1176, 128, 0, stream>>>(A, Wb, bias, out);
}

// Round 7
// 73.042 us; speedup vs baseline: 1.1476x; 1.0762x over previous
//
#include <hip/hip_runtime.h>
#include <stdint.h>

typedef __attribute__((ext_vector_type(8))) __bf16 bf16x8;
typedef __attribute__((ext_vector_type(4))) float f32x4;

__device__ __forceinline__ unsigned short f2bf(float f) {
  union { float f; unsigned int u; } v; v.f = f;
  unsigned int u = v.u;
  return (unsigned short)((u + 0x7fffu + ((u >> 16) & 1u)) >> 16);
}

__device__ __forceinline__ void async_copy16(const void* g, void* s) {
  __builtin_amdgcn_global_load_lds(
      (__attribute__((address_space(1))) void*)const_cast<void*>(g),
      (__attribute__((address_space(3))) void*)s,
      16, 0, 0);
}

#define HAAR(a, bb, cc, dd, oA, oH, oV, oD)                                    \
  oA = 0.5f * ((a + bb) + (cc + dd));                                          \
  oH = 0.5f * ((a + bb) - (cc + dd));                                          \
  oV = 0.5f * ((a - bb) + (cc - dd));                                          \
  oD = 0.5f * ((a - bb) - (cc - dd));

// ---------------- W fp32 -> bf16 (already [N=768][K=768] row-major) --------
__global__ __launch_bounds__(256) void convw_kernel(const float* __restrict__ W,
                                                    unsigned short* __restrict__ Wb) {
  int i = blockIdx.x * 256 + threadIdx.x;  // 147456 threads x 4 floats
  float4 v = ((const float4*)W)[i];
  uint2 o;
  o.x = (unsigned int)f2bf(v.x) | ((unsigned int)f2bf(v.y) << 16);
  o.y = (unsigned int)f2bf(v.z) | ((unsigned int)f2bf(v.w) << 16);
  ((uint2*)Wb)[i] = o;
}

// ------- 2-level Haar DWT -> bf16 A[M=25088][K=768] in patch layout --------
__global__ __launch_bounds__(256) void dwt2_kernel(const float* __restrict__ x,
                                                   unsigned short* __restrict__ A) {
  int tid = blockIdx.x * 256 + threadIdx.x;  // 128*3*56*56 = 1204224
  int J = tid % 56;
  int t = tid / 56;
  int I = t % 56;
  t /= 56;  // t = b*3 + c
  int c = t % 3;
  int b = t / 3;

  const float* xp = x + (((size_t)t * 224 + 4 * I) * 224 + 4 * J);
  float4 r0 = *(const float4*)(xp);
  float4 r1 = *(const float4*)(xp + 224);
  float4 r2 = *(const float4*)(xp + 448);
  float4 r3 = *(const float4*)(xp + 672);

  float A1[2][2], H1[2][2], V1[2][2], D1[2][2];
  HAAR(r0.x, r0.y, r1.x, r1.y, A1[0][0], H1[0][0], V1[0][0], D1[0][0]);
  HAAR(r0.z, r0.w, r1.z, r1.w, A1[0][1], H1[0][1], V1[0][1], D1[0][1]);
  HAAR(r2.x, r2.y, r3.x, r3.y, A1[1][0], H1[1][0], V1[1][0], D1[1][0]);
  HAAR(r2.z, r2.w, r3.z, r3.w, A1[1][1], H1[1][1], V1[1][1], D1[1][1]);

  auto aidx = [&](int y, int xx) -> size_t {
    int mrow = b * 196 + (y >> 4) * 14 + (xx >> 4);
    int k = c * 256 + (y & 15) * 16 + (xx & 15);
    return (size_t)mrow * 768 + (size_t)k;
  };
  auto store2 = [&](int y, int xx, float v0, float v1) {
    unsigned int p = (unsigned int)f2bf(v0) | ((unsigned int)f2bf(v1) << 16);
    *(unsigned int*)(A + aidx(y, xx)) = p;  // xx even -> 4B aligned, same patch
  };

  int y0 = 2 * I, x0 = 2 * J;
  store2(y0,           112 + x0, H1[0][0], H1[0][1]);
  store2(y0 + 1,       112 + x0, H1[1][0], H1[1][1]);
  store2(112 + y0,     x0,       V1[0][0], V1[0][1]);
  store2(112 + y0 + 1, x0,       V1[1][0], V1[1][1]);
  store2(112 + y0,     112 + x0, D1[0][0], D1[0][1]);
  store2(112 + y0 + 1, 112 + x0, D1[1][0], D1[1][1]);

  float vA2, vH2, vV2, vD2;
  HAAR(A1[0][0], A1[0][1], A1[1][0], A1[1][1], vA2, vH2, vV2, vD2);
  A[aidx(I,      J)]      = f2bf(vA2);
  A[aidx(I,      56 + J)] = f2bf(vH2);
  A[aidx(56 + I, J)]      = f2bf(vV2);
  A[aidx(56 + I, 56 + J)] = f2bf(vD2);
}

// --------- bf16 MFMA GEMM: C[M][N] = A[M][K] * Bt[N][K]^T + bias -----------
// M=25088, N=768, K=768. 128x128 block, BK=32, 4 waves of 64x64 (r3 geom).
// QUAD-buffered LDS (64 KB), prefetch depth 3 (tile t+3 staged during t),
// 2 compute phases/tile with setprio MFMA clusters, ONE barrier/tile with
// derived counted vmcnt (steady: 12 outstanding, wait vmcnt(8) = t+1 landed).
// r3's proven conflict-free chunk-XOR swizzle (pre-swizzled global source).
__global__ __launch_bounds__(256) void gemm_kernel(const unsigned short* __restrict__ A,
                                                   const unsigned short* __restrict__ Bt,
                                                   const float* __restrict__ bias,
                                                   float* __restrict__ C) {
  constexpr int K = 768, N = 768;
  constexpr int NT = 24;  // K / 32
  __shared__ unsigned short As[4][128 * 32];  // 8 KB per buffer
  __shared__ unsigned short Bs[4][128 * 32];

  // XCD swizzle: 1176 tiles = 8 XCDs x 147 consecutive tiles (bijective).
  const int orig = blockIdx.x;
  const int tile = (orig & 7) * 147 + (orig >> 3);
  const int bm = tile / 6, bn = tile % 6;

  const int tid = threadIdx.x;
  const int lane = tid & 63;
  const int wave = tid >> 6;
  const int wr = wave >> 1, wc = wave & 1;
  const int mbase = bm * 128, nbase = bn * 128;

  f32x4 acc[4][4] = {};

  // staging: per buffer, wave covers [wave*1024 + lane*16, +16) and +4096.
  // phys (row0, chunk kc0); source chunk pre-swizzled (involution).
  const int off0 = wave * 1024 + lane * 16;
  const int row0 = off0 >> 6;                    // 0..63
  const int kc0 = (off0 >> 4) & 3;
  const int kcs = kc0 ^ ((row0 >> 1) & 3);       // swizzled source chunk
  const unsigned short* ga0 = A + (size_t)(mbase + row0) * K + kcs * 8;
  const unsigned short* ga1 = ga0 + (size_t)64 * K;   // rows 64..127: same XOR
  const unsigned short* gb0 = Bt + (size_t)(nbase + row0) * K + kcs * 8;
  const unsigned short* gb1 = gb0 + (size_t)64 * K;

  auto stageA = [&](int buf, int kt) {
    char* sa = (char*)As + buf * 8192 + wave * 1024;
    async_copy16(ga0 + kt * 32, sa);
    async_copy16(ga1 + kt * 32, sa + 4096);
  };
  auto stageB = [&](int buf, int kt) {
    char* sb = (char*)Bs + buf * 8192 + wave * 1024;
    async_copy16(gb0 + kt * 32, sb);
    async_copy16(gb1 + kt * 32, sb + 4096);
  };

  const int fr = lane & 15;              // fragment row
  const int kq = lane >> 4;              // k-quarter (16B chunk)
  const int chq = kq ^ ((fr >> 1) & 3);  // swizzled read chunk

  // prologue: stage tiles 0,1,2 -> 12 outstanding; wait tile 0 (vmcnt 8).
  stageA(0, 0); stageB(0, 0);
  stageA(1, 1); stageB(1, 1);
  stageA(2, 2); stageB(2, 2);
  asm volatile("s_waitcnt vmcnt(8)" ::: "memory");
  __builtin_amdgcn_s_barrier();

#pragma unroll
  for (int kt = 0; kt < NT; ++kt) {
    const int cb = kt & 3;
    const char* pa = (const char*)As + cb * 8192 + (wr * 64 + fr) * 64 + chq * 16;
    const char* pb = (const char*)Bs + cb * 8192 + (wc * 64 + fr) * 64 + chq * 16;
    bf16x8 af[4], bv[4];

    // ---- phase 1: stage A(t+3) | read B0-3, A0-1 | 8 MFMA ----
    if (kt + 3 < NT) stageA((kt + 3) & 3, kt + 3);
#pragma unroll
    for (int ni = 0; ni < 4; ++ni) bv[ni] = *(const bf16x8*)(pb + ni * 1024);
    af[0] = *(const bf16x8*)(pa);
    af[1] = *(const bf16x8*)(pa + 1024);
    asm volatile("s_waitcnt lgkmcnt(0)" ::: "memory");
    __builtin_amdgcn_sched_barrier(0);
    __builtin_amdgcn_s_setprio(1);
#pragma unroll
    for (int mi = 0; mi < 2; ++mi)
#pragma unroll
      for (int ni = 0; ni < 4; ++ni)
        acc[mi][ni] = __builtin_amdgcn_mfma_f32_16x16x32_bf16(af[mi], bv[ni],
                                                              acc[mi][ni], 0, 0, 0);
    __builtin_amdgcn_s_setprio(0);

    // ---- phase 2: stage B(t+3) | read A2-3 | 8 MFMA ----
    if (kt + 3 < NT) stageB((kt + 3) & 3, kt + 3);
    af[2] = *(const bf16x8*)(pa + 2048);
    af[3] = *(const bf16x8*)(pa + 3072);
    asm volatile("s_waitcnt lgkmcnt(0)" ::: "memory");
    __builtin_amdgcn_sched_barrier(0);
    __builtin_amdgcn_s_setprio(1);
#pragma unroll
    for (int mi = 2; mi < 4; ++mi)
#pragma unroll
      for (int ni = 0; ni < 4; ++ni)
        acc[mi][ni] = __builtin_amdgcn_mfma_f32_16x16x32_bf16(af[mi], bv[ni],
                                                              acc[mi][ni], 0, 0, 0);
    __builtin_amdgcn_s_setprio(0);

    // ---- tile-end sync: counted wait (never drain mid-stream) ----
    if (kt <= NT - 4)
      asm volatile("s_waitcnt vmcnt(8)" ::: "memory");   // tile kt+1 landed
    else if (kt == NT - 3)
      asm volatile("s_waitcnt vmcnt(4)" ::: "memory");
    else if (kt == NT - 2)
      asm volatile("s_waitcnt vmcnt(0)" ::: "memory");
    if (kt < NT - 1) __builtin_amdgcn_s_barrier();
  }

  // epilogue: C col = lane&15, row = (lane>>4)*4 + j ; fuse bias
  const int rq = lane >> 4;
#pragma unroll
  for (int ni = 0; ni < 4; ++ni) {
    int n = nbase + wc * 64 + ni * 16 + fr;
    float bv = bias[n];
#pragma unroll
    for (int mi = 0; mi < 4; ++mi) {
      int mrow = mbase + wr * 64 + mi * 16 + rq * 4;
      f32x4 v = acc[mi][ni];
#pragma unroll
      for (int j = 0; j < 4; ++j) C[(size_t)(mrow + j) * N + n] = v[j] + bv;
    }
  }
}

extern "C" void kernel_launch(void* const* d_in, const int* in_sizes, int n_in,
                              void* d_out, int out_size, void* d_ws, size_t ws_size,
                              hipStream_t stream) {
  const float* x = (const float*)d_in[0];     // (128,3,224,224) f32
  const float* W = (const float*)d_in[1];     // (768,3,16,16)  f32
  const float* bias = (const float*)d_in[2];  // (768,)         f32
  float* out = (float*)d_out;                 // (128,196,768)  f32

  unsigned short* A = (unsigned short*)d_ws;                        // 25088*768 bf16
  unsigned short* Wb = (unsigned short*)((char*)d_ws + 38535168);   // 589824 bf16

  convw_kernel<<<576, 256, 0, stream>>>(W, Wb);
  dwt2_kernel<<<4704, 256, 0, stream>>>(x, A);
  gemm_kernel<<<1176, 256, 0, stream>>>(A, Wb, bias, out);
}